// Round 25
// baseline (220.966 us; speedup 1.0000x reference)
//
#include <hip/hip_runtime.h>

#define DIM     400
#define NENT    14541
#define B       32
#define NCAND   14505
#define DROWS   14560     // padded dense rows
#define CVTN    (DROWS * 50)                 // 728000 uint4
#define CVTBLK  ((CVTN + 255) / 256)         // 2844
#define NBLK    910       // score blocks: 8 pairs each (4 waves x 2 pairs)
#define THREADS 256

typedef __attribute__((ext_vector_type(2))) _Float16 half2_t;

static __device__ __forceinline__ half2_t bch(unsigned u) {
    return __builtin_bit_cast(half2_t, u);
}
static __device__ __forceinline__ half2_t habs2(half2_t x) {
    unsigned u = __builtin_bit_cast(unsigned, x) & 0x7fff7fffu;
    return __builtin_bit_cast(half2_t, u);
}
static __device__ __forceinline__ unsigned pkh(float x, float y) {
    half2_t h;
    h.x = (_Float16)x;
    h.y = (_Float16)y;
    return __builtin_bit_cast(unsigned, h);
}
static __device__ __forceinline__ float dot2acc(half2_t m, float s) {
#if __has_builtin(__builtin_amdgcn_fdot2)
    const half2_t ones = {(_Float16)1.f, (_Float16)1.f};
    return __builtin_amdgcn_fdot2(m, ones, s, false);
#else
    return s + (float)m.x + (float)m.y;
#endif
}

// ---- setup (R21 verbatim): dense16 = gathered f16 table; transposed q/o; base ----
__global__ void setup_kernel(const float* __restrict__ ent,
                             const float* __restrict__ relc,
                             const float* __restrict__ relo,
                             const float* __restrict__ onev,
                             const int*   __restrict__ pairs,
                             const int*   __restrict__ cidx,
                             uint4* __restrict__ dense16,
                             uint4* __restrict__ q16t,
                             uint4* __restrict__ o16t,
                             float* __restrict__ baseg) {
    const int blk = blockIdx.x;
    const int tid = threadIdx.x;
    if (blk < CVTBLK) {
        int i = blk * 256 + tid;                  // uint4 index: row*50 + col
        if (i >= CVTN) return;
        int row = i / 50;
        int col = i - row * 50;
        int n  = row < NCAND ? row : NCAND - 1;
        int ci = cidx[n];
        const float4* s4 = (const float4*)(ent + (size_t)ci * DIM) + col * 2;
        float4 a = s4[0], c = s4[1];
        uint4 d;
        d.x = pkh(a.x, a.y);
        d.y = pkh(a.z, a.w);
        d.z = pkh(c.x, c.y);
        d.w = pkh(c.z, c.w);
        dense16[i] = d;
    } else {
        const int b = blk - CVTBLK;
        const int h = pairs[2 * b + 0];
        const int r = pairs[2 * b + 1];
        float so = 0.f;
        if (tid < 50) {
            const float4* hp = (const float4*)(ent  + (size_t)h * DIM) + 2 * tid;
            const float4* cp = (const float4*)(relc + (size_t)r * DIM) + 2 * tid;
            const float4* op = (const float4*)(relo + (size_t)r * DIM) + 2 * tid;
            float4 h0 = hp[0], h1 = hp[1];
            float4 c0 = cp[0], c1 = cp[1];
            float4 v0 = op[0], v1 = op[1];
            uint4 qv, ov;
            qv.x = pkh(h0.x + c0.x, h0.y + c0.y);
            qv.y = pkh(h0.z + c0.z, h0.w + c0.w);
            qv.z = pkh(h1.x + c1.x, h1.y + c1.y);
            qv.w = pkh(h1.z + c1.z, h1.w + c1.w);
            ov.x = pkh(0.98f * v0.x, 0.98f * v0.y);
            ov.y = pkh(0.98f * v0.z, 0.98f * v0.w);
            ov.z = pkh(0.98f * v1.x, 0.98f * v1.y);
            ov.w = pkh(0.98f * v1.z, 0.98f * v1.w);
            q16t[tid * 32 + b] = qv;
            o16t[tid * 32 + b] = ov;
            so = v0.x + v0.y + v0.z + v0.w + v1.x + v1.y + v1.z + v1.w;
        }
        if (tid < 64) {
            so += __shfl_xor(so, 1);
            so += __shfl_xor(so, 2);
            so += __shfl_xor(so, 4);
            so += __shfl_xor(so, 8);
            so += __shfl_xor(so, 16);
            so += __shfl_xor(so, 32);
            if (tid == 0) baseg[b] = onev[0] + 0.98f * so;
        }
    }
}

// ---- main: R21's broadcast structure + REGISTER-PIPELINED candidate stream ----
// 102.4 KB LDS -> 1 block/CU -> 1 wave/SIMD ALWAYS. launch_bounds(256,1) frees the
// full 512-VGPR budget (the (256,2) in R21/R22/R24 made the allocator pick ~52 and
// expose every load's latency). Each wave computes its 2 pairs CONCURRENTLY (qj/oj
// ds_read once per j, feeds 2 cands) with quarter-row ping-pong register buffers
// (52 uint4 = 208 VGPR): quarter k+1's 24-26 global loads are in flight while
// quarter k's 80-VALU-per-j compute runs. ~26 loads/lane in flight covers L2 latency.
__global__ __launch_bounds__(THREADS, 1)
void score_f16(const uint4* __restrict__ dense16,
               const uint4* __restrict__ q16t,
               const uint4* __restrict__ o16t,
               const float* __restrict__ baseg,
               float* __restrict__ out) {
    __shared__ uint4 qs[1600];           // [j][b], j=0..49, b=0..31
    __shared__ uint4 os[1600];
    const int tid = threadIdx.x;
    for (int i = tid; i < 1600; i += THREADS) {
        qs[i] = q16t[i];
        os[i] = o16t[i];
    }
    __syncthreads();

    const int wid  = tid >> 6;           // 0..3
    const int lane = tid & 63;
    const int b    = lane & 31;          // batch
    const int c2   = lane >> 5;          // candidate within pair
    const float base = baseg[b];

    const int p0    = blockIdx.x * 8 + wid * 2;
    const int candA = 2 * p0 + c2;
    const int candB = candA + 2;         // next pair
    const uint4* rA = dense16 + (size_t)candA * 50;
    const uint4* rB = dense16 + (size_t)candB * 50;

    const half2_t K002 = {(_Float16)0.02f, (_Float16)0.02f};

#define PAIRE(cu, qu, ou, SS)                                   \
    {                                                           \
        half2_t cc_ = bch(cu), qq_ = bch(qu), oo_ = bch(ou);    \
        half2_t dd_ = cc_ - qq_;                                \
        half2_t aa_ = habs2(dd_);                               \
        half2_t ee_ = aa_ * K002 + oo_;                         \
        half2_t mm_ = __builtin_elementwise_max(aa_, ee_);      \
        SS = dot2acc(mm_, SS);                                  \
    }
#define PROC(C, Q, O, SA, SB)                                   \
    PAIRE(C.x, Q.x, O.x, SA) PAIRE(C.y, Q.y, O.y, SB)           \
    PAIRE(C.z, Q.z, O.z, SA) PAIRE(C.w, Q.w, O.w, SB)

#define LOADQ(buf, RP, S, L)                                    \
    _Pragma("unroll")                                           \
    for (int k = 0; k < (L); ++k) buf[k] = RP[(S) + k];

#define COMPQ(S, L, bufA, bufB)                                 \
    _Pragma("unroll")                                           \
    for (int k = 0; k < (L); ++k) {                             \
        const int j = (S) + k;                                  \
        const uint4 qj = qs[(j << 5) | b];                      \
        const uint4 oj = os[(j << 5) | b];                      \
        PROC(bufA[k], qj, oj, sA0, sA1)                         \
        PROC(bufB[k], qj, oj, sB0, sB1)                         \
    }

    float sA0 = 0.f, sA1 = 0.f, sB0 = 0.f, sB1 = 0.f;

    // quarter-row ping-pong: quarters [0,13) [13,26) [26,38) [38,50)
    uint4 a0[13], b0[13], a1[13], b1[13];        // 52 uint4 = 208 VGPR
    LOADQ(a0, rA, 0, 13)  LOADQ(b0, rB, 0, 13)   // Q0 in flight
    LOADQ(a1, rA, 13, 13) LOADQ(b1, rB, 13, 13)  // Q1 in flight
    COMPQ(0, 13, a0, b0)                         // compute Q0
    LOADQ(a0, rA, 26, 12) LOADQ(b0, rB, 26, 12)  // Q2 in flight
    COMPQ(13, 13, a1, b1)                        // compute Q1
    LOADQ(a1, rA, 38, 12) LOADQ(b1, rB, 38, 12)  // Q3 in flight
    COMPQ(26, 12, a0, b0)                        // compute Q2
    COMPQ(38, 12, a1, b1)                        // compute Q3

#undef COMPQ
#undef LOADQ
#undef PROC
#undef PAIRE

    if (candA < NCAND)
        out[(size_t)b * NCAND + candA] = base - (sA0 + sA1);
    if (candB < NCAND)
        out[(size_t)b * NCAND + candB] = base - (sB0 + sB1);
}

// ---- fallback (no ws): R9 f32 kernel verbatim ----
__global__ __launch_bounds__(THREADS, 2)
void score_f32(const float* __restrict__ ent,
               const float* __restrict__ relc,
               const float* __restrict__ relo,
               const float* __restrict__ onev,
               const int*   __restrict__ pairs,
               const int*   __restrict__ cidx,
               float* __restrict__ out) {
    const int fid  = blockIdx.x;
    const int xcd  = fid & 7;
    const int rest = fid >> 3;
    const int bq   = rest & 7;
    const int tc   = rest >> 3;
    const int t    = xcd + 8 * tc;

    const int tid  = threadIdx.x;
    const int lane = tid & 63;
    const int u    = lane & 15;
    const int g    = lane >> 4;
    const int b    = __builtin_amdgcn_readfirstlane(bq * 4 + (tid >> 6));

    const int hd = pairs[b * 2 + 0];
    const int rl = pairs[b * 2 + 1];
    const float4* hb = (const float4*)(ent  + (size_t)hd * DIM) + u;
    const float4* cb = (const float4*)(relc + (size_t)rl * DIM) + u;
    const float4* ob = (const float4*)(relo + (size_t)rl * DIM) + u;

    float4 q[7], o[7];
    float oa = 0.f;
#pragma unroll
    for (int k = 0; k < 6; ++k) {
        float4 h = hb[16 * k], c = cb[16 * k];
        q[k] = make_float4(h.x + c.x, h.y + c.y, h.z + c.z, h.w + c.w);
        o[k] = ob[16 * k];
        oa += o[k].x + o[k].y + o[k].z + o[k].w;
    }
    if (u < 4) {
        float4 h = hb[96], c = cb[96];
        q[6] = make_float4(h.x + c.x, h.y + c.y, h.z + c.z, h.w + c.w);
        o[6] = ob[96];
        oa += o[6].x + o[6].y + o[6].z + o[6].w;
    }
    oa += __shfl_xor(oa, 1);
    oa += __shfl_xor(oa, 2);
    oa += __shfl_xor(oa, 4);
    oa += __shfl_xor(oa, 8);
    const float base = onev[0] + 0.98f * oa;

    const float4* entu = (const float4*)ent + u;

#define E(vc, vq, vo, AM, AD)                     \
        {                                         \
            float d_ = (vc) - (vq);               \
            AM += fmaxf(fabsf(d_), (vo));         \
            AD += fabsf(d_);                      \
        }
#define F4(k, AM, AD)                             \
        E(cbuf[k].x, q[k].x, o[k].x, AM, AD)      \
        E(cbuf[k].y, q[k].y, o[k].y, AM, AD)      \
        E(cbuf[k].z, q[k].z, o[k].z, AM, AD)      \
        E(cbuf[k].w, q[k].w, o[k].w, AM, AD)

    for (int rr = t; rr < 3627; rr += 256) {
        const int cand = 4 * rr + g;
        const int ci   = cidx[cand < NCAND ? cand : NCAND - 1];
        const float4* p = entu + (size_t)ci * 100;

        float4 cbuf[7];
#pragma unroll
        for (int k = 0; k < 6; ++k) cbuf[k] = p[16 * k];
        if (u < 4) cbuf[6] = p[96];

        float am0 = 0.f, ad0 = 0.f, am1 = 0.f, ad1 = 0.f;
        F4(0, am0, ad0) F4(1, am1, ad1)
        F4(2, am0, ad0) F4(3, am1, ad1)
        F4(4, am0, ad0) F4(5, am1, ad1)
        if (u < 4) { F4(6, am0, ad0) }

        float s_ = fmaf(-0.98f, am0 + am1, -0.02f * (ad0 + ad1));
        s_ += __shfl_xor(s_, 1);
        s_ += __shfl_xor(s_, 2);
        s_ += __shfl_xor(s_, 4);
        s_ += __shfl_xor(s_, 8);

        if (u == 0 && cand < NCAND)
            out[(size_t)b * NCAND + cand] = base + s_;
    }
#undef F4
#undef E
}

extern "C" void kernel_launch(void* const* d_in, const int* in_sizes, int n_in,
                              void* d_out, int out_size, void* d_ws, size_t ws_size,
                              hipStream_t stream) {
    const float* ent   = (const float*)d_in[0];
    const float* relc  = (const float*)d_in[1];
    const float* relo  = (const float*)d_in[2];
    const float* onev  = (const float*)d_in[3];
    const int*   pairs = (const int*)d_in[4];
    const int*   cidx  = (const int*)d_in[5];
    float*       out   = (float*)d_out;

    const size_t denB = (size_t)DROWS * DIM * 2;     // 11,648,000 B
    const size_t qB   = (size_t)1600 * 16;           // 25,600 B per table
    const size_t need = denB + 2 * qB + B * sizeof(float);

    if (ws_size >= need) {
        unsigned char* w = (unsigned char*)d_ws;
        uint4* dense16 = (uint4*)w;
        uint4* q16t    = (uint4*)(w + denB);
        uint4* o16t    = (uint4*)(w + denB + qB);
        float* baseg   = (float*)(w + denB + 2 * qB);

        setup_kernel<<<CVTBLK + B, 256, 0, stream>>>(
            ent, relc, relo, onev, pairs, cidx, dense16, q16t, o16t, baseg);
        score_f16<<<NBLK, THREADS, 0, stream>>>(
            dense16, q16t, o16t, baseg, out);
    } else {
        score_f32<<<8 * 8 * 32, 256, 0, stream>>>(
            ent, relc, relo, onev, pairs, cidx, out);
    }
}

// Round 26
// 37.187 us; speedup vs baseline: 5.9420x; 5.9420x over previous
//
#include <hip/hip_runtime.h>

#define DIM     400
#define NENT    14541
#define B       32
#define NCAND   14505
#define PAIRS   7280      // candidate pairs (table padded to 14560 rows)
#define DROWS   14560
#define CVTN    (DROWS * 50)                 // 728000 uint4
#define CVTBLK  ((CVTN + 255) / 256)         // 2844
#define SBLOCKS (PAIRS / 8)                  // 910 score blocks (8 pairs each)
#define THREADS 256

typedef __attribute__((ext_vector_type(2))) _Float16 half2_t;

static __device__ __forceinline__ half2_t bch(unsigned u) {
    return __builtin_bit_cast(half2_t, u);
}
static __device__ __forceinline__ half2_t habs2(half2_t x) {
    unsigned u = __builtin_bit_cast(unsigned, x) & 0x7fff7fffu;
    return __builtin_bit_cast(half2_t, u);
}
static __device__ __forceinline__ unsigned pkh(float x, float y) {
    half2_t h;
    h.x = (_Float16)x;
    h.y = (_Float16)y;
    return __builtin_bit_cast(unsigned, h);
}
static __device__ __forceinline__ float dot2acc(half2_t m, float s) {
#if __has_builtin(__builtin_amdgcn_fdot2)
    const half2_t ones = {(_Float16)1.f, (_Float16)1.f};
    return __builtin_amdgcn_fdot2(m, ones, s, false);
#else
    return s + (float)m.x + (float)m.y;
#endif
}

// ---- merged setup ----
// blocks [0,CVTBLK): dense16[row] = f16(ent[cidx[row]])  (gather once, rows>=NCAND dup)
// blocks [CVTBLK, CVTBLK+32): TRANSPOSED q/o: q16t[j*32+b] = uint4 of 8 f16 dims
// [8j,8j+8) of batch b; o16t likewise (pre-scaled 0.98); baseg[b].
__global__ void setup_kernel(const float* __restrict__ ent,
                             const float* __restrict__ relc,
                             const float* __restrict__ relo,
                             const float* __restrict__ onev,
                             const int*   __restrict__ pairs,
                             const int*   __restrict__ cidx,
                             uint4* __restrict__ dense16,
                             uint4* __restrict__ q16t,
                             uint4* __restrict__ o16t,
                             float* __restrict__ baseg) {
    const int blk = blockIdx.x;
    const int tid = threadIdx.x;
    if (blk < CVTBLK) {
        int i = blk * THREADS + tid;              // uint4 index: row*50 + col
        if (i >= CVTN) return;
        int row = i / 50;
        int col = i - row * 50;
        int n  = row < NCAND ? row : NCAND - 1;
        int ci = cidx[n];
        const float4* s4 = (const float4*)(ent + (size_t)ci * DIM) + col * 2;
        float4 a = s4[0], c = s4[1];
        uint4 d;
        d.x = pkh(a.x, a.y);
        d.y = pkh(a.z, a.w);
        d.z = pkh(c.x, c.y);
        d.w = pkh(c.z, c.w);
        dense16[i] = d;
    } else {
        const int b = blk - CVTBLK;
        const int h = pairs[2 * b + 0];
        const int r = pairs[2 * b + 1];
        float so = 0.f;
        if (tid < 50) {
            const float4* hp = (const float4*)(ent  + (size_t)h * DIM) + 2 * tid;
            const float4* cp = (const float4*)(relc + (size_t)r * DIM) + 2 * tid;
            const float4* op = (const float4*)(relo + (size_t)r * DIM) + 2 * tid;
            float4 h0 = hp[0], h1 = hp[1];
            float4 c0 = cp[0], c1 = cp[1];
            float4 v0 = op[0], v1 = op[1];
            uint4 qv, ov;
            qv.x = pkh(h0.x + c0.x, h0.y + c0.y);
            qv.y = pkh(h0.z + c0.z, h0.w + c0.w);
            qv.z = pkh(h1.x + c1.x, h1.y + c1.y);
            qv.w = pkh(h1.z + c1.z, h1.w + c1.w);
            ov.x = pkh(0.98f * v0.x, 0.98f * v0.y);
            ov.y = pkh(0.98f * v0.z, 0.98f * v0.w);
            ov.z = pkh(0.98f * v1.x, 0.98f * v1.y);
            ov.w = pkh(0.98f * v1.z, 0.98f * v1.w);
            q16t[tid * 32 + b] = qv;
            o16t[tid * 32 + b] = ov;
            so = v0.x + v0.y + v0.z + v0.w + v1.x + v1.y + v1.z + v1.w;
        }
        if (tid < 64) {
            so += __shfl_xor(so, 1);
            so += __shfl_xor(so, 2);
            so += __shfl_xor(so, 4);
            so += __shfl_xor(so, 8);
            so += __shfl_xor(so, 16);
            so += __shfl_xor(so, 32);
            if (tid == 0) baseg[b] = onev[0] + 0.98f * so;
        }
    }
}

// ---- main: candidate row read ONCE, all 32 batches applied from LDS ----
// Block = 4 waves, 8 pairs. LDS = q/o for ALL batches, transposed [chunk j][batch b]
// (51.2 KB). Wave = 2 cands x 32 batches: lane (c2,b) owns output (cand,b) fully —
// no reduce, no re-reads. Per chunk: 1 broadcast glb load (L2-sequential) +
// 2 conflict-free contiguous ds_read_b128 + 20 packed f16 VALU.
__global__ __launch_bounds__(THREADS, 2)
void score_f16(const uint4* __restrict__ dense16,
               const uint4* __restrict__ q16t,
               const uint4* __restrict__ o16t,
               const float* __restrict__ baseg,
               float* __restrict__ out) {
    __shared__ uint4 qs[1600];           // [j][b] j=0..49, b=0..31
    __shared__ uint4 os[1600];
    const int tid = threadIdx.x;
    for (int i = tid; i < 1600; i += THREADS) {
        qs[i] = q16t[i];
        os[i] = o16t[i];
    }
    __syncthreads();

    const int wid  = tid >> 6;
    const int lane = tid & 63;
    const int b    = lane & 31;          // batch
    const int c2   = lane >> 5;          // candidate within pair
    const float base = baseg[b];

    const int p0 = blockIdx.x * 8 + wid * 2;   // 2 consecutive pairs per wave

    const half2_t K002 = {(_Float16)0.02f, (_Float16)0.02f};

#define PAIRE(cu, qu, ou, SS)                                   \
    {                                                           \
        half2_t cc_ = bch(cu), qq_ = bch(qu), oo_ = bch(ou);    \
        half2_t dd_ = cc_ - qq_;                                \
        half2_t aa_ = habs2(dd_);                               \
        half2_t ee_ = aa_ * K002 + oo_;                         \
        half2_t mm_ = __builtin_elementwise_max(aa_, ee_);      \
        SS = dot2acc(mm_, SS);                                  \
    }
#define PROC(C, Q, O, SA, SB)                                   \
    PAIRE(C.x, Q.x, O.x, SA) PAIRE(C.y, Q.y, O.y, SB)           \
    PAIRE(C.z, Q.z, O.z, SA) PAIRE(C.w, Q.w, O.w, SB)

#pragma unroll
    for (int pp = 0; pp < 2; ++pp) {
        const int pair = p0 + pp;
        const int cand = 2 * pair + c2;
        const uint4* cp = dense16 + (size_t)cand * 50;

        float s0 = 0.f, s1 = 0.f;
#pragma unroll 5
        for (int j = 0; j < 50; j += 2) {
            uint4 cj0 = cp[j];
            uint4 cj1 = cp[j + 1];
            uint4 qj0 = qs[j * 32 + b];
            uint4 oj0 = os[j * 32 + b];
            uint4 qj1 = qs[(j + 1) * 32 + b];
            uint4 oj1 = os[(j + 1) * 32 + b];
            PROC(cj0, qj0, oj0, s0, s1)
            PROC(cj1, qj1, oj1, s0, s1)
        }

        if (cand < NCAND)
            out[(size_t)b * NCAND + cand] = base - (s0 + s1);
    }
#undef PROC
#undef PAIRE
}

// ---- fallback (no ws): R9 f32 kernel verbatim ----
__global__ __launch_bounds__(THREADS, 2)
void score_f32(const float* __restrict__ ent,
               const float* __restrict__ relc,
               const float* __restrict__ relo,
               const float* __restrict__ onev,
               const int*   __restrict__ pairs,
               const int*   __restrict__ cidx,
               float* __restrict__ out) {
    const int fid  = blockIdx.x;
    const int xcd  = fid & 7;
    const int rest = fid >> 3;
    const int bq   = rest & 7;
    const int tc   = rest >> 3;
    const int t    = xcd + 8 * tc;

    const int tid  = threadIdx.x;
    const int lane = tid & 63;
    const int u    = lane & 15;
    const int g    = lane >> 4;
    const int b    = __builtin_amdgcn_readfirstlane(bq * 4 + (tid >> 6));

    const int hd = pairs[b * 2 + 0];
    const int rl = pairs[b * 2 + 1];
    const float4* hb = (const float4*)(ent  + (size_t)hd * DIM) + u;
    const float4* cb = (const float4*)(relc + (size_t)rl * DIM) + u;
    const float4* ob = (const float4*)(relo + (size_t)rl * DIM) + u;

    float4 q[7], o[7];
    float oa = 0.f;
#pragma unroll
    for (int k = 0; k < 6; ++k) {
        float4 h = hb[16 * k], c = cb[16 * k];
        q[k] = make_float4(h.x + c.x, h.y + c.y, h.z + c.z, h.w + c.w);
        o[k] = ob[16 * k];
        oa += o[k].x + o[k].y + o[k].z + o[k].w;
    }
    if (u < 4) {
        float4 h = hb[96], c = cb[96];
        q[6] = make_float4(h.x + c.x, h.y + c.y, h.z + c.z, h.w + c.w);
        o[6] = ob[96];
        oa += o[6].x + o[6].y + o[6].z + o[6].w;
    }
    oa += __shfl_xor(oa, 1);
    oa += __shfl_xor(oa, 2);
    oa += __shfl_xor(oa, 4);
    oa += __shfl_xor(oa, 8);
    const float base = onev[0] + 0.98f * oa;

    const float4* entu = (const float4*)ent + u;

#define E(vc, vq, vo, AM, AD)                     \
        {                                         \
            float d_ = (vc) - (vq);               \
            AM += fmaxf(fabsf(d_), (vo));         \
            AD += fabsf(d_);                      \
        }
#define F4(k, AM, AD)                             \
        E(cbuf[k].x, q[k].x, o[k].x, AM, AD)      \
        E(cbuf[k].y, q[k].y, o[k].y, AM, AD)      \
        E(cbuf[k].z, q[k].z, o[k].z, AM, AD)      \
        E(cbuf[k].w, q[k].w, o[k].w, AM, AD)

    for (int rr = t; rr < 3627; rr += 256) {
        const int cand = 4 * rr + g;
        const int ci   = cidx[cand < NCAND ? cand : NCAND - 1];
        const float4* p = entu + (size_t)ci * 100;

        float4 cbuf[7];
#pragma unroll
        for (int k = 0; k < 6; ++k) cbuf[k] = p[16 * k];
        if (u < 4) cbuf[6] = p[96];

        float am0 = 0.f, ad0 = 0.f, am1 = 0.f, ad1 = 0.f;
        F4(0, am0, ad0) F4(1, am1, ad1)
        F4(2, am0, ad0) F4(3, am1, ad1)
        F4(4, am0, ad0) F4(5, am1, ad1)
        if (u < 4) { F4(6, am0, ad0) }

        float s_ = fmaf(-0.98f, am0 + am1, -0.02f * (ad0 + ad1));
        s_ += __shfl_xor(s_, 1);
        s_ += __shfl_xor(s_, 2);
        s_ += __shfl_xor(s_, 4);
        s_ += __shfl_xor(s_, 8);

        if (u == 0 && cand < NCAND)
            out[(size_t)b * NCAND + cand] = base + s_;
    }
#undef F4
#undef E
}

extern "C" void kernel_launch(void* const* d_in, const int* in_sizes, int n_in,
                              void* d_out, int out_size, void* d_ws, size_t ws_size,
                              hipStream_t stream) {
    const float* ent   = (const float*)d_in[0];
    const float* relc  = (const float*)d_in[1];
    const float* relo  = (const float*)d_in[2];
    const float* onev  = (const float*)d_in[3];
    const int*   pairs = (const int*)d_in[4];
    const int*   cidx  = (const int*)d_in[5];
    float*       out   = (float*)d_out;

    const size_t denB = (size_t)DROWS * DIM * 2;     // 11,648,000 B
    const size_t qB   = (size_t)1600 * 16;           // 25,600 B per table
    const size_t need = denB + 2 * qB + B * sizeof(float);

    if (ws_size >= need) {
        unsigned char* w = (unsigned char*)d_ws;
        uint4* dense16 = (uint4*)w;
        uint4* q16t    = (uint4*)(w + denB);
        uint4* o16t    = (uint4*)(w + denB + qB);
        float* baseg   = (float*)(w + denB + 2 * qB);

        setup_kernel<<<CVTBLK + B, THREADS, 0, stream>>>(
            ent, relc, relo, onev, pairs, cidx, dense16, q16t, o16t, baseg);
        score_f16<<<SBLOCKS, THREADS, 0, stream>>>(
            dense16, q16t, o16t, baseg, out);
    } else {
        score_f32<<<8 * 8 * 32, THREADS, 0, stream>>>(
            ent, relc, relo, onev, pairs, cidx, out);
    }
}